// Round 4
// baseline (260.214 us; speedup 1.0000x reference)
//
#include <hip/hip_runtime.h>

// ExemplarNoAttention: logits[b,c] = log( sum_{e: label[e]==c} exp(-beta*d2[b,e]) + eps )
// d2[b,e] = ||x_b||^2 + ||e_e||^2 - 2<x_b,e_e>, clamped >= 0; beta = softplus(beta_raw).
//
// Round 4: R3 was latency-stalled (VALUBusy 22%, 980 cyc/iter vs ~70 of work).
//  (a) XCD-sharded e-chunks: 104 chunks, XCD k (= blockIdx&7) only touches chunks
//      == k mod 8 -> 832 KB/XCD working set fits per-XCD L2; ex_h HBM-fetched once.
//  (b) branchless 1-deep register prefetch of next subtile's frags (+unroll 4).
//  (c) log() fused into main via per-btile done counter (saves a launch).
// Segment-sum stays as the onehot-MFMA (R2): zero atomics in the inner loop.

#define NB      1024
#define NE      50000
#define NCHUNK  104
#define NE_PAD  (NCHUNK * 512)   // 53248
#define KD      64
#define NC      10

using half8   = __attribute__((ext_vector_type(8))) _Float16;  // 16x16x32 A/B frag (4 VGPRs)
using half4v  = __attribute__((ext_vector_type(4))) _Float16;  // 16x16x16 A/B frag (2 VGPRs)
using floatx4 = __attribute__((ext_vector_type(4))) float;

__device__ __forceinline__ float softplus_f(float x) {
  return (x > 20.f) ? x : log1pf(__expf(x));
}

// ---------------------------------------------------------------------------
// prep: cast x/exemplars to fp16, cb = -beta*||x||^2, ce = -beta*||e||^2,
// padded labels, zero class_sims + done counters. 16 lanes per row, 16 rows/block.
// Pad rows [NE, NE_PAD): ex_h = 0, ce = -1e30 (=> sim exactly 0), label 0.
// ---------------------------------------------------------------------------
__global__ __launch_bounds__(256) void prep_kernel(
    const float* __restrict__ x, const float* __restrict__ ex,
    const int* __restrict__ labels, const float* __restrict__ beta_raw,
    _Float16* __restrict__ ex_h, float* __restrict__ ce,
    _Float16* __restrict__ x_h, float* __restrict__ cb,
    float* __restrict__ class_sims, int* __restrict__ lab_pad,
    int* __restrict__ done_cnt)
{
  const int tid = threadIdx.x;
  const int gid = blockIdx.x * 256 + tid;
  if (gid < NB * NC) class_sims[gid] = 0.f;
  if (gid < 16) done_cnt[gid] = 0;

  const float beta = softplus_f(beta_raw[0]);

  const int row = blockIdx.x * 16 + (tid >> 4);  // 3392 blocks cover NE_PAD + NB rows
  const int l16 = tid & 15;

  if (row < NE_PAD) {
    float4 v = make_float4(0.f, 0.f, 0.f, 0.f);
    if (row < NE) v = ((const float4*)ex)[row * 16 + l16];
    half4v hv = { (_Float16)v.x, (_Float16)v.y, (_Float16)v.z, (_Float16)v.w };
    *(half4v*)(ex_h + (size_t)row * KD + l16 * 4) = hv;
    float s = v.x*v.x + v.y*v.y + v.z*v.z + v.w*v.w;
    #pragma unroll
    for (int m = 1; m < 16; m <<= 1) s += __shfl_xor(s, m, 64);
    if (l16 == 0) ce[row] = (row < NE) ? (-beta * s) : -1e30f;
    if (l16 == 1) lab_pad[row] = (row < NE) ? labels[row] : 0;
  } else {
    const int rx = row - NE_PAD;  // [0, NB)
    float4 v = ((const float4*)x)[rx * 16 + l16];
    half4v hv = { (_Float16)v.x, (_Float16)v.y, (_Float16)v.z, (_Float16)v.w };
    *(half4v*)(x_h + (size_t)rx * KD + l16 * 4) = hv;
    float s = v.x*v.x + v.y*v.y + v.z*v.z + v.w*v.w;
    #pragma unroll
    for (int m = 1; m < 16; m <<= 1) s += __shfl_xor(s, m, 64);
    if (l16 == 0) cb[rx] = -beta * s;
  }
}

// ---------------------------------------------------------------------------
// main: 1D grid of 1664 blocks. xcd = id&7, j = id>>3; chunk = xcd + 8*(j%13),
// btile = j/13. So each XCD owns 13 chunks x 16 btiles (832 KB of ex_h -> L2-resident).
// Block = 4 waves, no LDS in the loop. Wave w owns batch cols [btile*64+16w, +16).
// MFMA1 (16x16x32): D1[e=quad*4+r][b=l15] = <ex_e, x_b>. Epilogue exp -> fp16 p,
// which is exactly the 16x16x16 B-operand frag. MFMA2: acc[c][b] += onehot . p.
// Branchless 1-deep prefetch of next subtile's frags hides L2 latency.
// Last block per btile (done counter) computes the 640 logits (fused log kernel).
// ---------------------------------------------------------------------------
__global__ __launch_bounds__(256) void main_kernel(
    const _Float16* __restrict__ ex_h, const float* __restrict__ ce,
    const _Float16* __restrict__ x_h, const float* __restrict__ cb,
    const int* __restrict__ lab_pad, const float* __restrict__ beta_raw,
    float* __restrict__ class_sims, int* __restrict__ done_cnt,
    float* __restrict__ out)
{
  const int tid  = threadIdx.x;
  const int wave = tid >> 6;
  const int lane = tid & 63;
  const int l15  = lane & 15;
  const int quad = lane >> 4;

  const int id    = blockIdx.x;
  const int xcd   = id & 7;
  const int j     = id >> 3;
  const int chunk = xcd + 8 * (j % 13);
  const int btile = j / 13;
  const int e0    = chunk * 512;
  const int bm    = btile * 64 + wave * 16;

  const float beta = softplus_f(beta_raw[0]);
  const float s2 = 2.f * beta;

  // x B-frags: B[k=quad*8+j][n=l15] -> x row-major, loaded once.
  const half8* xrow = (const half8*)(x_h + (size_t)(bm + l15) * KD);
  const half8 bx0 = xrow[quad];
  const half8 bx1 = xrow[quad + 4];
  const float cbl = cb[bm + l15];

  // lane-fixed base pointers for the e-subtile stream (stride 16 rows = 1024 halfs)
  const _Float16* ebase = ex_h + (size_t)(e0 + l15) * KD + quad * 8;
  const float*    cbase = ce + e0 + quad * 4;
  const int*      lbase = lab_pad + e0 + quad * 4;

  // prefetch subtile 0
  half8  nae0 = *(const half8*)(ebase);
  half8  nae1 = *(const half8*)(ebase + 32);
  float4 nce  = *(const float4*)(cbase);
  int4   nlb  = *(const int4*)(lbase);

  floatx4 acc = {0.f, 0.f, 0.f, 0.f};

  #pragma unroll 4
  for (int s = 0; s < 32; ++s) {
    const half8  ae0 = nae0;
    const half8  ae1 = nae1;
    const float4 ce4 = nce;
    const int4   lb4 = nlb;

    // branchless prefetch of next subtile (last iter re-loads subtile 31)
    const int sn = (s < 31) ? (s + 1) : 31;
    const _Float16* ep = ebase + (size_t)sn * 1024;
    nae0 = *(const half8*)(ep);
    nae1 = *(const half8*)(ep + 32);
    nce  = *(const float4*)(cbase + (size_t)sn * 16);
    nlb  = *(const int4*)(lbase + (size_t)sn * 16);

    floatx4 d = {0.f, 0.f, 0.f, 0.f};
    d = __builtin_amdgcn_mfma_f32_16x16x32_f16(ae0, bx0, d, 0, 0, 0);
    d = __builtin_amdgcn_mfma_f32_16x16x32_f16(ae1, bx1, d, 0, 0, 0);

    const float cef[4] = { ce4.x, ce4.y, ce4.z, ce4.w };
    half4v p;
    #pragma unroll
    for (int r = 0; r < 4; ++r) {
      const float t = fminf(fmaf(s2, d[r], cbl + cef[r]), 0.f);  // -beta*max(d2,0)
      p[r] = (_Float16)__expf(t);
    }

    half4v oh;
    oh[0] = (lb4.x == l15) ? (_Float16)1.f : (_Float16)0.f;
    oh[1] = (lb4.y == l15) ? (_Float16)1.f : (_Float16)0.f;
    oh[2] = (lb4.z == l15) ? (_Float16)1.f : (_Float16)0.f;
    oh[3] = (lb4.w == l15) ? (_Float16)1.f : (_Float16)0.f;

    acc = __builtin_amdgcn_mfma_f32_16x16x16f16(oh, p, acc, 0, 0, 0);
  }

  // acc: lane holds class_part[c = quad*4+r][b = l15] -> one global atomic per cell.
  #pragma unroll
  for (int r = 0; r < 4; ++r) {
    const int c = quad * 4 + r;
    if (c < NC) {
      __hip_atomic_fetch_add(&class_sims[(size_t)(bm + l15) * NC + c], acc[r],
                             __ATOMIC_RELAXED, __HIP_MEMORY_SCOPE_AGENT);
    }
  }

  // fused finalize: last block to finish this btile writes its 640 logits.
  __shared__ int lastflag;
  __threadfence();      // make this block's atomics agent-visible
  __syncthreads();
  if (tid == 0) {
    const int prev = __hip_atomic_fetch_add(&done_cnt[btile], 1,
                                            __ATOMIC_ACQ_REL, __HIP_MEMORY_SCOPE_AGENT);
    lastflag = (prev == NCHUNK - 1);
  }
  __syncthreads();
  if (lastflag) {
    __threadfence();
    const int base = btile * 64 * NC;
    for (int i = tid; i < 64 * NC; i += 256) {
      const float v = __hip_atomic_load(&class_sims[base + i],
                                        __ATOMIC_RELAXED, __HIP_MEMORY_SCOPE_AGENT);
      out[base + i] = __logf(v + 1e-12f);
    }
  }
}

extern "C" void kernel_launch(void* const* d_in, const int* in_sizes, int n_in,
                              void* d_out, int out_size, void* d_ws, size_t ws_size,
                              hipStream_t stream)
{
  const float* x        = (const float*)d_in[0];
  const float* ex       = (const float*)d_in[1];
  const int*   labels   = (const int*)d_in[2];
  const float* beta_raw = (const float*)d_in[3];
  float* out = (float*)d_out;

  // Workspace layout (~7.42 MB total):
  char* ws = (char*)d_ws;
  _Float16* ex_h       = (_Float16*)ws;             // 53248*64*2 = 6,815,744 B
  float*    ce         = (float*)(ws + 6815744);    //   212,992 B
  _Float16* x_h        = (_Float16*)(ws + 7028736); //   131,072 B
  float*    cb         = (float*)(ws + 7159808);    //     4,096 B
  float*    class_sims = (float*)(ws + 7163904);    //    40,960 B
  int*      lab_pad    = (int*)(ws + 7204864);      //   212,992 B
  int*      done_cnt   = (int*)(ws + 7417856);      //        64 B (end: 7,417,920)

  prep_kernel<<<3392, 256, 0, stream>>>(x, ex, labels, beta_raw,
                                        ex_h, ce, x_h, cb, class_sims, lab_pad, done_cnt);
  main_kernel<<<1664, 256, 0, stream>>>(ex_h, ce, x_h, cb, lab_pad, beta_raw,
                                        class_sims, done_cnt, out);
}

// Round 5
// 208.607 us; speedup vs baseline: 1.2474x; 1.2474x over previous
//
#include <hip/hip_runtime.h>

// ExemplarNoAttention: logits[b,c] = log( sum_{e: label[e]==c} exp(-beta*d2[b,e]) + eps )
// d2[b,e] = ||x_b||^2 + ||e_e||^2 - 2<x_b,e_e>, clamped >= 0; beta = softplus(beta_raw).
//
// Round 5:
//  - R4 regression root-caused to agent-scope fences in the fused finalize
//    (buffer_inv per block end invalidated per-XCD L2 -> co-resident blocks ran at
//    L3 latency; FETCH dropped 26.7->4.1 MB yet dur 80->199 us). Fences removed;
//    finalize is a separate tiny kernel again (kernel boundary = ordering).
//  - XCD shard kept (it provably cut HBM traffic 6.5x): 104 chunks, XCD k = id&7
//    owns chunks == k (mod 8) -> 1.7 MB fp32 shard is L2-resident.
//  - prep_kernel DELETED (was part of a fixed ~60 us residual): main reads fp32
//    x/ex directly, converts to fp16 in-register, computes -beta*||e||^2 into LDS
//    per block and -beta*||x||^2 per wave via shfl. ws = 40 KB class_sims only.
// Segment-sum stays the onehot-MFMA (zero atomics in the loop; relaxed global
// atomics at block end only).

#define NB      1024
#define NE      50000
#define NCHUNK  104
#define CHUNK   512
#define KD      64
#define NC      10

using half8   = __attribute__((ext_vector_type(8))) _Float16;  // 16x16x32 A/B frag (4 VGPRs)
using half4v  = __attribute__((ext_vector_type(4))) _Float16;  // 16x16x16 A/B frag (2 VGPRs)
using floatx4 = __attribute__((ext_vector_type(4))) float;

__device__ __forceinline__ float softplus_f(float x) {
  return (x > 20.f) ? x : log1pf(__expf(x));
}

// ---------------------------------------------------------------------------
// main: 1664 blocks = 8 XCDs x 13 chunks x 16 btiles. xcd = id&7, j = id>>3,
// chunk = xcd + 8*(j%13), btile = j/13. Block = 4 waves + 2 KB LDS (ce of its
// 512-row chunk). Wave w owns batch cols [btile*64+16w, +16).
// Setup: ce_lds[r] = -beta*||e_{e0+r}||^2 (pad rows: -1e30 -> sim exactly 0);
//        per-wave x B-frags (fp32->fp16) + cbl = -beta*||x_b||^2 (shfl over quads).
// Loop (32 subtiles of 16 e-rows): load fp32 e-rows (L2-resident shard), cvt fp16,
//   MFMA1 16x16x32 -> d[e][b]; p = exp(min(2*beta*d + cbl + ce, 0)) as fp16
//   (= the 16x16x16 B-frag); MFMA2 vs onehot labels -> acc[c][b] in AGPRs.
// Flush: one relaxed global fp32 atomic per (b, c<10) cell. NO fences.
// ---------------------------------------------------------------------------
__global__ __launch_bounds__(256) void main_kernel(
    const float* __restrict__ x, const float* __restrict__ ex,
    const int* __restrict__ labels, const float* __restrict__ beta_raw,
    float* __restrict__ class_sims)
{
  __shared__ float ce_lds[CHUNK];

  const int tid  = threadIdx.x;
  const int wave = tid >> 6;
  const int lane = tid & 63;
  const int l15  = lane & 15;
  const int quad = lane >> 4;

  const int id    = blockIdx.x;
  const int xcd   = id & 7;
  const int j     = id >> 3;
  const int chunk = xcd + 8 * (j % 13);
  const int btile = j / 13;
  const int e0    = chunk * CHUNK;
  const int bm    = btile * 64 + wave * 16;

  const float beta = softplus_f(beta_raw[0]);
  const float s2 = 2.f * beta;

  // --- setup A: ce_lds for this block's 512 chunk rows (2 rows/thread) ---
  #pragma unroll
  for (int h = 0; h < 2; ++h) {
    const int r = tid + h * 256;
    const int e = e0 + r;
    if (e < NE) {
      const float4* rp = (const float4*)(ex + (size_t)e * KD);
      float s = 0.f;
      #pragma unroll
      for (int q = 0; q < 16; ++q) {
        const float4 v = rp[q];
        s += v.x*v.x + v.y*v.y + v.z*v.z + v.w*v.w;
      }
      ce_lds[r] = -beta * s;
    } else {
      ce_lds[r] = -1e30f;   // pad row -> p = exp(-inf) = 0
    }
  }

  // --- setup B: x B-frags (B[k=quad*8+j][n=l15]) from fp32 + cbl ---
  const float4* xr = (const float4*)(x + (size_t)(bm + l15) * KD);
  const float4 xv0 = xr[quad * 2];
  const float4 xv1 = xr[quad * 2 + 1];
  const float4 xv2 = xr[8 + quad * 2];
  const float4 xv3 = xr[8 + quad * 2 + 1];
  const half8 bx0 = { (_Float16)xv0.x, (_Float16)xv0.y, (_Float16)xv0.z, (_Float16)xv0.w,
                      (_Float16)xv1.x, (_Float16)xv1.y, (_Float16)xv1.z, (_Float16)xv1.w };
  const half8 bx1 = { (_Float16)xv2.x, (_Float16)xv2.y, (_Float16)xv2.z, (_Float16)xv2.w,
                      (_Float16)xv3.x, (_Float16)xv3.y, (_Float16)xv3.z, (_Float16)xv3.w };
  float p2 = xv0.x*xv0.x + xv0.y*xv0.y + xv0.z*xv0.z + xv0.w*xv0.w
           + xv1.x*xv1.x + xv1.y*xv1.y + xv1.z*xv1.z + xv1.w*xv1.w
           + xv2.x*xv2.x + xv2.y*xv2.y + xv2.z*xv2.z + xv2.w*xv2.w
           + xv3.x*xv3.x + xv3.y*xv3.y + xv3.z*xv3.z + xv3.w*xv3.w;
  p2 += __shfl_xor(p2, 16, 64);   // quads 0..3 each hold 16 of the 64 k's
  p2 += __shfl_xor(p2, 32, 64);
  const float cbl = -beta * p2;

  __syncthreads();

  floatx4 acc = {0.f, 0.f, 0.f, 0.f};

  #pragma unroll 2
  for (int s = 0; s < 32; ++s) {
    const int ebase = e0 + s * 16;
    // A-frag: A[m=l15][k=quad*8+j] from fp32 ex (clamped row for pads; junk dot
    // is killed by ce=-1e30). 4x float4 -> cvt to 2x half8.
    const int er = min(ebase + l15, NE - 1);
    const float4* ap = (const float4*)(ex + (size_t)er * KD) + quad * 2;
    const float4 a0 = ap[0];
    const float4 a1 = ap[1];
    const float4 a2 = ap[8];
    const float4 a3 = ap[9];
    const half8 ae0 = { (_Float16)a0.x, (_Float16)a0.y, (_Float16)a0.z, (_Float16)a0.w,
                        (_Float16)a1.x, (_Float16)a1.y, (_Float16)a1.z, (_Float16)a1.w };
    const half8 ae1 = { (_Float16)a2.x, (_Float16)a2.y, (_Float16)a2.z, (_Float16)a2.w,
                        (_Float16)a3.x, (_Float16)a3.y, (_Float16)a3.z, (_Float16)a3.w };

    // per-quad broadcasts: ce (LDS, conflict-free/broadcast) + labels (clamped
    // int4; NE%4==0 so no mixed real/pad group is ever clamped).
    const float4 ce4 = *(const float4*)(ce_lds + s * 16 + quad * 4);
    const int4   lb4 = *(const int4*)(labels + min(ebase + quad * 4, NE - 4));

    floatx4 d = {0.f, 0.f, 0.f, 0.f};
    d = __builtin_amdgcn_mfma_f32_16x16x32_f16(ae0, bx0, d, 0, 0, 0);
    d = __builtin_amdgcn_mfma_f32_16x16x32_f16(ae1, bx1, d, 0, 0, 0);

    const float cef[4] = { ce4.x, ce4.y, ce4.z, ce4.w };
    half4v p;
    #pragma unroll
    for (int r = 0; r < 4; ++r) {
      const float t = fminf(fmaf(s2, d[r], cbl + cef[r]), 0.f);  // -beta*max(d2,0)
      p[r] = (_Float16)__expf(t);
    }

    half4v oh;
    oh[0] = (lb4.x == l15) ? (_Float16)1.f : (_Float16)0.f;
    oh[1] = (lb4.y == l15) ? (_Float16)1.f : (_Float16)0.f;
    oh[2] = (lb4.z == l15) ? (_Float16)1.f : (_Float16)0.f;
    oh[3] = (lb4.w == l15) ? (_Float16)1.f : (_Float16)0.f;

    acc = __builtin_amdgcn_mfma_f32_16x16x16f16(oh, p, acc, 0, 0, 0);
  }

  // acc: lane holds class_part[c = quad*4+r][b = l15] -> relaxed global atomics.
  #pragma unroll
  for (int r = 0; r < 4; ++r) {
    const int c = quad * 4 + r;
    if (c < NC) {
      __hip_atomic_fetch_add(&class_sims[(size_t)(bm + l15) * NC + c], acc[r],
                             __ATOMIC_RELAXED, __HIP_MEMORY_SCOPE_AGENT);
    }
  }
}

// ---------------------------------------------------------------------------
// finalize: logits = log(class_sims + eps). Kernel boundary orders the atomics.
// ---------------------------------------------------------------------------
__global__ __launch_bounds__(256) void log_kernel(
    const float* __restrict__ cs, float* __restrict__ out)
{
  const int i = blockIdx.x * 256 + threadIdx.x;
  if (i < NB * NC) out[i] = __logf(cs[i] + 1e-12f);
}

extern "C" void kernel_launch(void* const* d_in, const int* in_sizes, int n_in,
                              void* d_out, int out_size, void* d_ws, size_t ws_size,
                              hipStream_t stream)
{
  const float* x        = (const float*)d_in[0];
  const float* ex       = (const float*)d_in[1];
  const int*   labels   = (const int*)d_in[2];
  const float* beta_raw = (const float*)d_in[3];
  float* out = (float*)d_out;

  float* class_sims = (float*)d_ws;   // 1024*10*4 = 40,960 B

  hipMemsetAsync(class_sims, 0, NB * NC * sizeof(float), stream);
  main_kernel<<<1664, 256, 0, stream>>>(x, ex, labels, beta_raw, class_sims);
  log_kernel<<<40, 256, 0, stream>>>(class_sims, out);
}

// Round 6
// 102.639 us; speedup vs baseline: 2.5352x; 2.0324x over previous
//
#include <hip/hip_runtime.h>

// ExemplarNoAttention: logits[b,c] = log( sum_{e: label[e]==c} exp(-beta*d2[b,e]) + eps )
// d2[b,e] = ||x_b||^2 + ||e_e||^2 - 2<x_b,e_e>, clamped >= 0; beta = softplus(beta_raw).
//
// Round 6 = R3 (best known: 80 us main) + canonical LDS double-buffered staging.
//  - R3/R4/R5 all stall-bound (~1000-1700 cyc/iter, all pipes idle): raw global
//    latency on the frag loads, 4 waves/block redundantly loading the SAME e-rows.
//  - Fix (GEMM-ladder m93->m97 pattern): stage 64-row e-subtiles into LDS once per
//    block, double-buffered; next stage's global loads are issued into registers
//    BEFORE computing the current stage from LDS (vmcnt chain independent of the
//    ds_read lgkmcnt chain -> latency hidden behind ~600 cyc of compute).
//  - LDS rows padded 64->72 halfs (144 B): ds_read_b128 banks = 4*(l15+quad) mod 32
//    -> 2-way aliasing (free, m136); 144 = 9*16 keeps 16 B alignment.
//  - prep kernel restored (R5 proved the ~60 us residual is harness overhead, not
//    prep). Segment-sum stays the onehot-MFMA; relaxed atomics at block end only.

#define NB      1024
#define NE      50000
#define NE_PAD  50176    // 98 chunks * 512
#define KD      64
#define NC      10
#define SROWS   64       // e-rows per stage
#define NSTAGE  8        // 512 / SROWS
#define LROW    72       // padded LDS row stride in halfs (144 B)

using half8   = __attribute__((ext_vector_type(8))) _Float16;  // 16x16x32 A/B frag (4 VGPRs)
using half4v  = __attribute__((ext_vector_type(4))) _Float16;  // 16x16x16 A/B frag (2 VGPRs)
using floatx4 = __attribute__((ext_vector_type(4))) float;

__device__ __forceinline__ float softplus_f(float x) {
  return (x > 20.f) ? x : log1pf(__expf(x));
}

// ---------------------------------------------------------------------------
// prep: cast x/exemplars to fp16, cb = -beta*||x||^2, ce = -beta*||e||^2,
// padded labels, zero class_sims. 16 lanes/row, 16 rows/block, 3200 blocks.
// Pad rows [NE, NE_PAD): ex_h = 0, ce = -1e30 (=> sim exactly 0), label 0.
// ---------------------------------------------------------------------------
__global__ __launch_bounds__(256) void prep_kernel(
    const float* __restrict__ x, const float* __restrict__ ex,
    const int* __restrict__ labels, const float* __restrict__ beta_raw,
    _Float16* __restrict__ ex_h, float* __restrict__ ce,
    _Float16* __restrict__ x_h, float* __restrict__ cb,
    float* __restrict__ class_sims, int* __restrict__ lab_pad)
{
  const int tid = threadIdx.x;
  const int gid = blockIdx.x * 256 + tid;
  if (gid < NB * NC) class_sims[gid] = 0.f;

  const float beta = softplus_f(beta_raw[0]);

  const int row = blockIdx.x * 16 + (tid >> 4);  // 3200*16 = 51200 = NE_PAD + NB
  const int l16 = tid & 15;

  if (row < NE_PAD) {
    float4 v = make_float4(0.f, 0.f, 0.f, 0.f);
    if (row < NE) v = ((const float4*)ex)[row * 16 + l16];
    half4v hv = { (_Float16)v.x, (_Float16)v.y, (_Float16)v.z, (_Float16)v.w };
    *(half4v*)(ex_h + (size_t)row * KD + l16 * 4) = hv;
    float s = v.x*v.x + v.y*v.y + v.z*v.z + v.w*v.w;
    #pragma unroll
    for (int m = 1; m < 16; m <<= 1) s += __shfl_xor(s, m, 64);
    if (l16 == 0) ce[row] = (row < NE) ? (-beta * s) : -1e30f;
    if (l16 == 1) lab_pad[row] = (row < NE) ? labels[row] : 0;
  } else {
    const int rx = row - NE_PAD;  // [0, NB)
    float4 v = ((const float4*)x)[rx * 16 + l16];
    half4v hv = { (_Float16)v.x, (_Float16)v.y, (_Float16)v.z, (_Float16)v.w };
    *(half4v*)(x_h + (size_t)rx * KD + l16 * 4) = hv;
    float s = v.x*v.x + v.y*v.y + v.z*v.z + v.w*v.w;
    #pragma unroll
    for (int m = 1; m < 16; m <<= 1) s += __shfl_xor(s, m, 64);
    if (l16 == 0) cb[rx] = -beta * s;
  }
}

// ---------------------------------------------------------------------------
// main: grid (16 btiles, 98 chunks), block = 4 waves. Wave w owns batch cols
// [btile*64+16w, +16) (B-frags from x_h, loaded once). Per stage (64 e-rows):
//   prefetch next stage global->regs, compute 4 subtiles from LDS buf,
//   barrier, write regs->other buf, barrier.
// Subtile: ae from LDS (padded, 2-way banks), ce/lab LDS broadcast,
//   MFMA1 16x16x32 -> d[e][b]; p = exp(min(2*beta*d + cb + ce, 0)) fp16
//   (= 16x16x16 B-frag); MFMA2 vs onehot labels -> acc[c][b] in AGPRs.
// Flush: one relaxed global fp32 atomic per (b, c<10) cell.
// ---------------------------------------------------------------------------
__global__ __launch_bounds__(256) void main_kernel(
    const _Float16* __restrict__ ex_h, const float* __restrict__ ce,
    const _Float16* __restrict__ x_h, const float* __restrict__ cb,
    const int* __restrict__ lab_pad, const float* __restrict__ beta_raw,
    float* __restrict__ class_sims)
{
  __shared__ _Float16 Ah[2][SROWS * LROW];
  __shared__ float    Ce[2][SROWS];
  __shared__ int      Lb[2][SROWS];

  const int tid  = threadIdx.x;
  const int wave = tid >> 6;
  const int lane = tid & 63;
  const int l15  = lane & 15;
  const int quad = lane >> 4;

  const int btile = blockIdx.x;
  const int chunk = blockIdx.y;
  const int e0    = chunk * 512;
  const int bm    = btile * 64 + wave * 16;

  const float beta = softplus_f(beta_raw[0]);
  const float s2 = 2.f * beta;

  // x B-frags: B[k=quad*8+j][n=l15] -> x_h row-major, loaded once per wave.
  const half8* xrow = (const half8*)(x_h + (size_t)(bm + l15) * KD);
  const half8 bx0 = xrow[quad];
  const half8 bx1 = xrow[quad + 4];
  const float cbl = cb[bm + l15];

  // stage-load lane constants: thread t moves 32 B of row (t>>2), halfs [(t&3)*16..)
  const int srow = tid >> 2;
  const int scol = tid & 3;
  const _Float16* gsrc = ex_h + (size_t)(e0 + srow) * KD + scol * 16;
  const int lofs = srow * LROW + scol * 16;

  // ---- prologue: stage 0 global -> regs -> LDS buf 0 ----
  half8 pr0 = *(const half8*)(gsrc);
  half8 pr1 = *(const half8*)(gsrc + 8);
  float prc = 0.f; int prl = 0;
  if (wave == 0) prc = ce[e0 + lane];
  if (wave == 1) prl = lab_pad[e0 + lane];

  *(half8*)(&Ah[0][lofs])     = pr0;
  *(half8*)(&Ah[0][lofs + 8]) = pr1;
  if (wave == 0) Ce[0][lane] = prc;
  if (wave == 1) Lb[0][lane] = prl;
  __syncthreads();

  floatx4 acc = {0.f, 0.f, 0.f, 0.f};

  for (int st = 0; st < NSTAGE; ++st) {
    const int b = st & 1;

    // prefetch next stage into registers (loads stay in flight during compute:
    // vmcnt chain, independent of the ds_read lgkmcnt chain below)
    if (st + 1 < NSTAGE) {
      const _Float16* g = gsrc + (size_t)(st + 1) * SROWS * KD;
      pr0 = *(const half8*)(g);
      pr1 = *(const half8*)(g + 8);
      if (wave == 0) prc = ce[e0 + (st + 1) * SROWS + lane];
      if (wave == 1) prl = lab_pad[e0 + (st + 1) * SROWS + lane];
    }

    // compute 4 subtiles of 16 e-rows from LDS buf b
    #pragma unroll
    for (int sub = 0; sub < 4; ++sub) {
      const int abase = (sub * 16 + l15) * LROW + quad * 8;
      const half8 ae0 = *(const half8*)(&Ah[b][abase]);
      const half8 ae1 = *(const half8*)(&Ah[b][abase + 32]);
      const float4 ce4 = *(const float4*)(&Ce[b][sub * 16 + quad * 4]);
      const int4   lb4 = *(const int4*)(&Lb[b][sub * 16 + quad * 4]);

      floatx4 d = {0.f, 0.f, 0.f, 0.f};
      d = __builtin_amdgcn_mfma_f32_16x16x32_f16(ae0, bx0, d, 0, 0, 0);
      d = __builtin_amdgcn_mfma_f32_16x16x32_f16(ae1, bx1, d, 0, 0, 0);

      const float cef[4] = { ce4.x, ce4.y, ce4.z, ce4.w };
      half4v p;
      #pragma unroll
      for (int r = 0; r < 4; ++r) {
        const float t = fminf(fmaf(s2, d[r], cbl + cef[r]), 0.f);  // -beta*max(d2,0)
        p[r] = (_Float16)__expf(t);
      }

      half4v oh;
      oh[0] = (lb4.x == l15) ? (_Float16)1.f : (_Float16)0.f;
      oh[1] = (lb4.y == l15) ? (_Float16)1.f : (_Float16)0.f;
      oh[2] = (lb4.z == l15) ? (_Float16)1.f : (_Float16)0.f;
      oh[3] = (lb4.w == l15) ? (_Float16)1.f : (_Float16)0.f;

      acc = __builtin_amdgcn_mfma_f32_16x16x16f16(oh, p, acc, 0, 0, 0);
    }

    // swap: everyone done reading buf (st+1)&1 (last touched in stage st-1),
    // write next stage into it, make visible.
    if (st + 1 < NSTAGE) {
      __syncthreads();
      const int nb = (st + 1) & 1;
      *(half8*)(&Ah[nb][lofs])     = pr0;
      *(half8*)(&Ah[nb][lofs + 8]) = pr1;
      if (wave == 0) Ce[nb][lane] = prc;
      if (wave == 1) Lb[nb][lane] = prl;
      __syncthreads();
    }
  }

  // acc: lane holds class_part[c = quad*4+r][b = l15] -> relaxed global atomics.
  #pragma unroll
  for (int r = 0; r < 4; ++r) {
    const int c = quad * 4 + r;
    if (c < NC) {
      __hip_atomic_fetch_add(&class_sims[(size_t)(bm + l15) * NC + c], acc[r],
                             __ATOMIC_RELAXED, __HIP_MEMORY_SCOPE_AGENT);
    }
  }
}

// ---------------------------------------------------------------------------
// finalize: logits = log(class_sims + eps). Kernel boundary orders the atomics.
// ---------------------------------------------------------------------------
__global__ __launch_bounds__(256) void log_kernel(
    const float* __restrict__ cs, float* __restrict__ out)
{
  const int i = blockIdx.x * 256 + threadIdx.x;
  if (i < NB * NC) out[i] = __logf(cs[i] + 1e-12f);
}

extern "C" void kernel_launch(void* const* d_in, const int* in_sizes, int n_in,
                              void* d_out, int out_size, void* d_ws, size_t ws_size,
                              hipStream_t stream)
{
  const float* x        = (const float*)d_in[0];
  const float* ex       = (const float*)d_in[1];
  const int*   labels   = (const int*)d_in[2];
  const float* beta_raw = (const float*)d_in[3];
  float* out = (float*)d_out;

  // Workspace layout (~7.0 MB total):
  char* ws = (char*)d_ws;
  _Float16* ex_h       = (_Float16*)ws;             // 50176*64*2 = 6,422,528 B
  float*    ce         = (float*)(ws + 6422528);    //   200,704 B
  _Float16* x_h        = (_Float16*)(ws + 6623232); //   131,072 B
  float*    cb         = (float*)(ws + 6754304);    //     4,096 B
  float*    class_sims = (float*)(ws + 6758400);    //    40,960 B
  int*      lab_pad    = (int*)(ws + 6799360);      //   200,704 B  (end: 7,000,064)

  prep_kernel<<<3200, 256, 0, stream>>>(x, ex, labels, beta_raw,
                                        ex_h, ce, x_h, cb, class_sims, lab_pad);
  dim3 g(16, 98);
  main_kernel<<<g, 256, 0, stream>>>(ex_h, ce, x_h, cb, lab_pad, beta_raw, class_sims);
  log_kernel<<<40, 256, 0, stream>>>(class_sims, out);
}